// Round 13
// baseline (932.788 us; speedup 1.0000x reference)
//
#include <hip/hip_runtime.h>

// ---------------------------------------------------------------------------
// H2Q knot kernel: embed -> 8 doubling quaternion expansion steps ->
// 6 quaternion-linear+normalize layers -> vocab head (+ stability loss).
// R18: single GEMM family. gemm_8ph deleted; E6/E7 move onto the proven
// gemm8p body (new EPI 0), head on gemm_head (R17, correct). Rationale:
// R17's +50us non-layer regression was unattributable between gemm_8ph
// rule-#19 codegen perturbation / gemm_head / noise -> remove the confound.
// Arithmetic also favors gemm8p for E6/E7 (256/512 blocks all-resident at
// 2 blocks/CU vs 8ph's 1 block/CU): E6 ~11us, E7 ~22us predicted.
//  - layers: R8 ring-3 128n x 256m gemm8p, 2 blocks/CU (87-89.5 us).
//  - E4/E5: gemm_epi0 (small K).
//  - head: gemm_head, grid (3,128), WH 384 rows, masked n<257.
// ---------------------------------------------------------------------------

typedef _Float16 f16x8 __attribute__((ext_vector_type(8)));
typedef float    f32x4 __attribute__((ext_vector_type(4)));

#define GL2LDS16(gp, lp) __builtin_amdgcn_global_load_lds(                     \
    (const __attribute__((address_space(1))) void*)(gp),                       \
    (__attribute__((address_space(3))) void*)(lp), 16, 0, 0)

__device__ __forceinline__ unsigned short f2h(float f) {
  union { _Float16 h; unsigned short u; } c;
  c.h = (_Float16)f;                       // RNE
  return c.u;
}
__device__ __forceinline__ float h2f(unsigned short u) {
  union { unsigned short u; _Float16 h; } c;
  c.u = u;
  return (float)c.h;
}

// ---------------------------------------------------------------------------
// Weight expansion: quaternion weights [4][cq][cq] -> real fp16 matrix
// E[n][k], n=4o+a (out), k=4i+b (in), rows >= 4cq zero-padded.
// ---------------------------------------------------------------------------
__global__ __launch_bounds__(256) void expand_ham(
    const float* __restrict__ w, unsigned short* __restrict__ out,
    int cq, int kbits, int total) {
  int id = blockIdx.x * 256 + threadIdx.x;
  if (id >= total) return;
  const int K = 1 << kbits;
  const int n = id >> kbits;
  const int k = id & (K - 1);
  float val = 0.f;
  if (n < 4 * cq) {
    const int o = n >> 2, a = n & 3, i = k >> 2, b = k & 3;
    const int   comp[4][4] = {{0,1,2,3},{1,0,3,2},{2,3,0,1},{3,2,1,0}};
    const float sgn [4][4] = {{1.f,-1.f,-1.f,-1.f},{1.f,1.f,1.f,-1.f},
                              {1.f,-1.f,1.f,1.f},{1.f,1.f,-1.f,1.f}};
    val = sgn[a][b] * w[comp[a][b] * cq * cq + o * cq + i];
  }
  out[id] = f2h(val);
}

// All 6 layer weights (cq=256) in one kernel: w [6][4][256][256] -> E
// [6][1024][1024] fp16.
__global__ __launch_bounds__(256) void expand_ham6(
    const float* __restrict__ w, unsigned short* __restrict__ out) {
  const int id = blockIdx.x * 256 + threadIdx.x;   // 6*1024*1024 threads
  const int d = id >> 20;
  const int r = id & 1048575;
  const int n = r >> 10, k = r & 1023;
  const int o = n >> 2, a = n & 3, i = k >> 2, b = k & 3;
  const int   comp[4][4] = {{0,1,2,3},{1,0,3,2},{2,3,0,1},{3,2,1,0}};
  const float sgn [4][4] = {{1.f,-1.f,-1.f,-1.f},{1.f,1.f,1.f,-1.f},
                            {1.f,-1.f,1.f,1.f},{1.f,1.f,-1.f,1.f}};
  const float val =
      sgn[a][b] * w[d * 262144 + comp[a][b] * 65536 + o * 256 + i];
  out[id] = f2h(val);
}

// Head weights padded to 384 rows (zero-filled), exact fit for 3 n-tiles
// of 128 on gemm_head.
__global__ __launch_bounds__(256) void conv_head(
    const float* __restrict__ wh, unsigned short* __restrict__ out) {
  int id = blockIdx.x * 256 + threadIdx.x;   // 384*1024 threads
  int v = id >> 10, k = id & 1023;
  out[id] = f2h(v < 257 ? wh[v * 1024 + k] : 0.f);
}

// ---------------------------------------------------------------------------
// Embed + expansion steps 0..3 (cq=1,2,4,8), one token per thread (weights
// wave-uniform -> scalar-cached broadcast loads). Output fp16 [32768][64].
// ---------------------------------------------------------------------------
template <int CQ>
__device__ __forceinline__ void exp_step(float (&q)[16][4],
                                         const float* __restrict__ w) {
  float d[CQ][4];
#pragma unroll
  for (int o = 0; o < CQ; o++) {
    float pr = 0.f, pi = 0.f, pj = 0.f, pk = 0.f;
#pragma unroll
    for (int i = 0; i < CQ; i++) {
      const float wr = w[0 * CQ * CQ + o * CQ + i];
      const float wi = w[1 * CQ * CQ + o * CQ + i];
      const float wj = w[2 * CQ * CQ + o * CQ + i];
      const float wk = w[3 * CQ * CQ + o * CQ + i];
      const float qr = q[i][0], qi = q[i][1], qj = q[i][2], qk = q[i][3];
      pr += wr * qr - wi * qi - wj * qj - wk * qk;
      pi += wi * qr + wr * qi + wk * qj - wj * qk;
      pj += wj * qr - wk * qi + wr * qj + wi * qk;
      pk += wk * qr + wj * qi - wi * qj + wr * qk;
    }
    d[o][0] = tanhf(pr); d[o][1] = tanhf(pi);
    d[o][2] = tanhf(pj); d[o][3] = tanhf(pk);
  }
#pragma unroll
  for (int o = 0; o < CQ; o++)
#pragma unroll
    for (int a = 0; a < 4; a++) {
      const float dd = d[o][a], qq = q[o][a];
      q[o][a]      = qq + dd;
      q[CQ + o][a] = qq - dd;
    }
}

__global__ __launch_bounds__(256) void embed_expand(
    const int* __restrict__ x, const float* __restrict__ emb,
    const float* __restrict__ w0, const float* __restrict__ w1,
    const float* __restrict__ w2, const float* __restrict__ w3,
    unsigned short* __restrict__ out) {
  const int t = blockIdx.x * 256 + threadIdx.x;  // 32768 tokens
  float q[16][4];
  const int v = x[t];
  const float4 e = *(const float4*)(emb + v * 4);
  q[0][0] = e.x; q[0][1] = e.y; q[0][2] = e.z; q[0][3] = e.w;
  exp_step<1>(q, w0);
  exp_step<2>(q, w1);
  exp_step<4>(q, w2);
  exp_step<8>(q, w3);
  ushort4* o4 = (ushort4*)(out + (size_t)t * 64);
#pragma unroll
  for (int c = 0; c < 16; c++) {
    ushort4 u;
    u.x = f2h(q[c][0]); u.y = f2h(q[c][1]);
    u.z = f2h(q[c][2]); u.w = f2h(q[c][3]);
    o4[c] = u;
  }
}

// ---------------------------------------------------------------------------
// Old 128x128 fused GEMM, kept only for small expansion steps E4/E5 (EPI 0).
// ---------------------------------------------------------------------------
__global__ __launch_bounds__(256) void gemm_epi0(
    const unsigned short* __restrict__ W,
    const unsigned short* __restrict__ Act,
    unsigned short* __restrict__ OutB,
    int K, int Nreal, int ldout) {
  __shared__ unsigned short WtL[128 * 32];
  __shared__ unsigned short WtH[128 * 32];
  __shared__ unsigned short AtL[128 * 32];
  __shared__ unsigned short AtH[128 * 32];

  const int tid  = threadIdx.x;
  const int wave = tid >> 6;
  const int lane = tid & 63;
  const int l15  = lane & 15;
  const int quad = lane >> 4;

  const int Gx = gridDim.x;
  const int L  = blockIdx.y * Gx + blockIdx.x;
  const int j  = L & 7;
  const int s  = L >> 3;
  const int nblock = (s % Gx) * 128;               // n (output feature)
  const int mblock = (32 * j + s / Gx) * 128;      // token
  const int wn = (wave & 1) * 64;
  const int wm = (wave >> 1) * 64;

  f32x4 acc[4][4];
  const f32x4 zero = {0.f, 0.f, 0.f, 0.f};
#pragma unroll
  for (int a = 0; a < 4; a++)
#pragma unroll
    for (int b = 0; b < 4; b++) acc[a][b] = zero;

  const int row0 = tid >> 2;
  const int sub  = tid & 3;
  const unsigned short* gW0 = W   + (size_t)(nblock + row0)      * K + sub * 8;
  const unsigned short* gW1 = W   + (size_t)(nblock + row0 + 64) * K + sub * 8;
  const unsigned short* gA0 = Act + (size_t)(mblock + row0)      * K + sub * 8;
  const unsigned short* gA1 = Act + (size_t)(mblock + row0 + 64) * K + sub * 8;
  unsigned short* lWL0 = &WtL[wave * 512];
  unsigned short* lWL1 = &WtL[2048 + wave * 512];
  unsigned short* lWH0 = &WtH[wave * 512];
  unsigned short* lWH1 = &WtH[2048 + wave * 512];
  unsigned short* lAL0 = &AtL[wave * 512];
  unsigned short* lAL1 = &AtL[2048 + wave * 512];
  unsigned short* lAH0 = &AtH[wave * 512];
  unsigned short* lAH1 = &AtH[2048 + wave * 512];

  for (int kb = 0; kb < K; kb += 64) {
    GL2LDS16(gW0 + kb,      lWL0);
    GL2LDS16(gW1 + kb,      lWL1);
    GL2LDS16(gW0 + kb + 32, lWH0);
    GL2LDS16(gW1 + kb + 32, lWH1);
    GL2LDS16(gA0 + kb,      lAL0);
    GL2LDS16(gA1 + kb,      lAL1);
    GL2LDS16(gA0 + kb + 32, lAH0);
    GL2LDS16(gA1 + kb + 32, lAH1);
    __syncthreads();

    {
      f16x8 afr[4], bfr[4];
#pragma unroll
      for (int tn = 0; tn < 4; tn++)
        afr[tn] = *(const f16x8*)&WtL[(wn + tn * 16 + l15) * 32 + quad * 8];
#pragma unroll
      for (int tm = 0; tm < 4; tm++)
        bfr[tm] = *(const f16x8*)&AtL[(wm + tm * 16 + l15) * 32 + quad * 8];
#pragma unroll
      for (int tn = 0; tn < 4; tn++)
#pragma unroll
        for (int tm = 0; tm < 4; tm++)
          acc[tn][tm] = __builtin_amdgcn_mfma_f32_16x16x32_f16(
              afr[tn], bfr[tm], acc[tn][tm], 0, 0, 0);
    }
    {
      f16x8 afr[4], bfr[4];
#pragma unroll
      for (int tn = 0; tn < 4; tn++)
        afr[tn] = *(const f16x8*)&WtH[(wn + tn * 16 + l15) * 32 + quad * 8];
#pragma unroll
      for (int tm = 0; tm < 4; tm++)
        bfr[tm] = *(const f16x8*)&AtH[(wm + tm * 16 + l15) * 32 + quad * 8];
#pragma unroll
      for (int tn = 0; tn < 4; tn++)
#pragma unroll
        for (int tm = 0; tm < 4; tm++)
          acc[tn][tm] = __builtin_amdgcn_mfma_f32_16x16x32_f16(
              afr[tn], bfr[tm], acc[tn][tm], 0, 0, 0);
    }
    __syncthreads();
  }

  // expansion step epilogue
#pragma unroll
  for (int tn = 0; tn < 4; tn++) {
    const int n = nblock + wn + tn * 16 + quad * 4;
    if (n < Nreal) {
#pragma unroll
      for (int tm = 0; tm < 4; tm++) {
        const int token = mblock + wm + tm * 16 + l15;
        const f32x4 v = acc[tn][tm];
        const unsigned short* ip = Act + (size_t)token * K + n;
        const float i0 = h2f(ip[0]), i1 = h2f(ip[1]);
        const float i2 = h2f(ip[2]), i3 = h2f(ip[3]);
        const float d0 = tanhf(v[0]), d1 = tanhf(v[1]);
        const float d2 = tanhf(v[2]), d3 = tanhf(v[3]);
        ushort4 up, um;
        up.x = f2h(i0 + d0); up.y = f2h(i1 + d1);
        up.z = f2h(i2 + d2); up.w = f2h(i3 + d3);
        um.x = f2h(i0 - d0); um.y = f2h(i1 - d1);
        um.z = f2h(i2 - d2); um.w = f2h(i3 - d3);
        *(ushort4*)&OutB[(size_t)token * ldout + n] = up;
        *(ushort4*)&OutB[(size_t)token * ldout + Nreal + n] = um;
      }
    }
  }
}

// ---------------------------------------------------------------------------
// R8 layer GEMM family: 128n x 256m, 8 waves (2x4) of 64x64, ring-3 24KB
// LDS bufs (72 KB), launch_bounds(512,4) -> ~60 VGPR -> 2 blocks/CU resident
// (cross-block LDS/MFMA anti-phasing, m114 — best measured: 87-89.5
// us/layer). Per K-tile(32): 8 ds_read_b128 + stage kt+2 (3 glds) ->
// barrier -> lgkmcnt(0)+sched_barrier -> setprio'd 16 MFMA -> counted
// vmcnt(3) -> barrier. T2 swizzle: read halfword-off ^((l15&6)<<2), inverse
// on source k-slot. C/D: col=token=lane&15, row=n=(lane>>4)*4+reg.
// EPI: 0 = expansion step (delta=tanh, write q+delta | q-delta; NW=Nreal)
//      1 = qnormalize -> fp16 [token][1024]
//      2 = EPI1 + stability loss.
// ---------------------------------------------------------------------------
template <int EPI>
__global__ __launch_bounds__(512, 4) void gemm8p(
    const unsigned short* __restrict__ W,
    const unsigned short* __restrict__ Act,
    unsigned short* __restrict__ OutB, float* __restrict__ OutF,
    int K, int NW, int ldout) {
  __shared__ unsigned short S[3 * 12288];   // ring-3: [W 4096 | B 8192] ush
  __shared__ float lsum[8];

  const int tid  = threadIdx.x;
  const int wave = tid >> 6;
  const int lane = tid & 63;
  const int l15  = lane & 15;
  const int quad = lane >> 4;
  const int wr   = wave >> 2;          // 0..1  n half (64 rows)
  const int wc   = wave & 3;           // 0..3  token quarter (64 cols)

  // XCD swizzle: xcd j = L%8 owns m-tiles [j*Gy/8, (j+1)*Gy/8), n fastest
  const int Gx = gridDim.x;
  const int L  = blockIdx.y * Gx + blockIdx.x;
  const int j  = L & 7;
  const int s  = L >> 3;
  const int mblock = (j * (gridDim.y >> 3) + s / Gx) * 256;   // token
  const int nblock = (s % Gx) * 128;                          // n
  const int NT = K >> 5;               // K-tiles of 32

  f32x4 acc[4][4];
  const f32x4 zero = {0.f, 0.f, 0.f, 0.f};
#pragma unroll
  for (int a = 0; a < 4; a++)
#pragma unroll
    for (int b = 0; b < 4; b++) acc[a][b] = zero;

  // Staging: thread t -> row t>>2, 16B slot t&3 of the 64B k-row.
  // Source k-slot inverse-swizzled: sl = (t&3) ^ ((row&6)>>1).
  const int rw = tid >> 2;                       // 0..127
  const int sl = (tid & 3) ^ ((tid >> 3) & 3);
  const int wrow = nblock + rw;
  const int cwr  = wrow < NW ? wrow : NW - 1;    // clamp (exact fit at all
                                                 // current call sites)
  const unsigned short* sW  = W   + (size_t)cwr * K + sl * 8;
  const unsigned short* sB0 = Act + (size_t)(mblock + rw)       * K + sl * 8;
  const unsigned short* sB1 = Act + (size_t)(mblock + 128 + rw) * K + sl * 8;

  // Read-side swizzle: rows are X*16+l15 -> row&6 == l15&6, constant per lane
  const int swz = (quad * 8) ^ ((l15 & 6) << 2);   // halfword offset XOR

  // prologue: stage tiles 0,1 into bufs 0,1 (3 glds each)
#pragma unroll
  for (int t = 0; t < 2; ++t) {
    unsigned short* d = S + t * 12288 + tid * 8;
    GL2LDS16(sW  + t * 32, d);
    GL2LDS16(sB0 + t * 32, d + 4096);
    GL2LDS16(sB1 + t * 32, d + 8192);
  }
  asm volatile("s_waitcnt vmcnt(3)" ::: "memory");   // tile 0 landed
  __builtin_amdgcn_s_barrier();
  __builtin_amdgcn_sched_barrier(0);

  int bC = 0;   // buffer holding tile kt
  int bS = 2;   // buffer receiving tile kt+2
  for (int kt = 0; kt < NT; ++kt) {
    const unsigned short* SA = S + bC * 12288;
    const unsigned short* SB = SA + 4096;

    f16x8 af[4], bf[4];
#pragma unroll
    for (int t4 = 0; t4 < 4; t4++)
      af[t4] = *(const f16x8*)(SA + (wr * 64 + t4 * 16 + l15) * 32 + swz);
#pragma unroll
    for (int t4 = 0; t4 < 4; t4++)
      bf[t4] = *(const f16x8*)(SB + (wc * 64 + t4 * 16 + l15) * 32 + swz);

    // stage tile kt+2 into buf bS (read last at tile kt-1; reads drained
    // before the previous boundary barrier)
    if (kt + 2 < NT) {
      const int kb = (kt + 2) * 32;
      unsigned short* d = S + bS * 12288 + tid * 8;
      GL2LDS16(sW  + kb, d);
      GL2LDS16(sB0 + kb, d + 4096);
      GL2LDS16(sB1 + kb, d + 8192);
    }

    __builtin_amdgcn_s_barrier();
    asm volatile("s_waitcnt lgkmcnt(0)" ::: "memory");
    __builtin_amdgcn_sched_barrier(0);
    __builtin_amdgcn_s_setprio(1);
#pragma unroll
    for (int tn = 0; tn < 4; tn++)
#pragma unroll
      for (int tm = 0; tm < 4; tm++)
        acc[tn][tm] = __builtin_amdgcn_mfma_f32_16x16x32_f16(
            af[tn], bf[tm], acc[tn][tm], 0, 0, 0);
    __builtin_amdgcn_s_setprio(0);

    // boundary: tile kt+1 must have landed; keep kt+2 in flight (counted)
    if (kt < NT - 1) {
      if (kt + 2 < NT) asm volatile("s_waitcnt vmcnt(3)" ::: "memory");
      else             asm volatile("s_waitcnt vmcnt(0)" ::: "memory");
      __builtin_amdgcn_s_barrier();
      __builtin_amdgcn_sched_barrier(0);
    }
    bC = bC == 2 ? 0 : bC + 1;
    bS = bS == 2 ? 0 : bS + 1;
  }

  if constexpr (EPI == 0) {
    // expansion step: write q+delta at [token*ldout+n], q-delta at +NW
#pragma unroll
    for (int tn = 0; tn < 4; tn++) {
      const int n = nblock + wr * 64 + tn * 16 + quad * 4;
#pragma unroll
      for (int tm = 0; tm < 4; tm++) {
        const int token = mblock + wc * 64 + tm * 16 + l15;
        const f32x4 v = acc[tn][tm];
        const unsigned short* ip = Act + (size_t)token * K + n;
        const float i0 = h2f(ip[0]), i1 = h2f(ip[1]);
        const float i2 = h2f(ip[2]), i3 = h2f(ip[3]);
        const float d0 = tanhf(v[0]), d1 = tanhf(v[1]);
        const float d2 = tanhf(v[2]), d3 = tanhf(v[3]);
        ushort4 up, um;
        up.x = f2h(i0 + d0); up.y = f2h(i1 + d1);
        up.z = f2h(i2 + d2); up.w = f2h(i3 + d3);
        um.x = f2h(i0 - d0); um.y = f2h(i1 - d1);
        um.z = f2h(i2 - d2); um.w = f2h(i3 - d3);
        *(ushort4*)&OutB[(size_t)token * ldout + n] = up;
        *(ushort4*)&OutB[(size_t)token * ldout + NW + n] = um;
      }
    }
  } else {
    float loss = 0.f;
#pragma unroll
    for (int tn = 0; tn < 4; tn++) {
      const int n = nblock + wr * 64 + tn * 16 + quad * 4;
#pragma unroll
      for (int tm = 0; tm < 4; tm++) {
        const int token = mblock + wc * 64 + tm * 16 + l15;
        const f32x4 v = acc[tn][tm];
        const float nrm =
            sqrtf(v[0] * v[0] + v[1] * v[1] + v[2] * v[2] + v[3] * v[3]);
        const float inv = 1.f / (nrm + 1e-8f);
        ushort4 u;
        u.x = f2h(v[0] * inv); u.y = f2h(v[1] * inv);
        u.z = f2h(v[2] * inv); u.w = f2h(v[3] * inv);
        *(ushort4*)&OutB[(size_t)token * 1024 + n] = u;
        if constexpr (EPI == 2) loss += fabsf(v[0] * inv);
      }
    }
    if constexpr (EPI == 2) {
#pragma unroll
      for (int off = 32; off > 0; off >>= 1) loss += __shfl_down(loss, off);
      if (lane == 0) lsum[wave] = loss;
      __syncthreads();
      if (tid == 0) {
        float t = 0.f;
#pragma unroll
        for (int w8 = 0; w8 < 8; w8++) t += lsum[w8];
        atomicAdd(OutF, t * (1.f / 8388608.f));
      }
    }
  }
}

// ---------------------------------------------------------------------------
// gemm_head: head GEMM (gemm8p body + fp32 head epilogue). 128n x 256m,
// grid (3,128) = 384 blocks, W = WH (384 exact rows), stores masked n<257.
// ---------------------------------------------------------------------------
__global__ __launch_bounds__(512, 4) void gemm_head(
    const unsigned short* __restrict__ W,
    const unsigned short* __restrict__ Act,
    float* __restrict__ OutF, int K) {
  __shared__ unsigned short S[3 * 12288];

  const int tid  = threadIdx.x;
  const int wave = tid >> 6;
  const int lane = tid & 63;
  const int l15  = lane & 15;
  const int quad = lane >> 4;
  const int wr   = wave >> 2;
  const int wc   = wave & 3;

  const int Gx = gridDim.x;
  const int L  = blockIdx.y * Gx + blockIdx.x;
  const int j  = L & 7;
  const int s  = L >> 3;
  const int mblock = (j * (gridDim.y >> 3) + s / Gx) * 256;   // token
  const int nblock = (s % Gx) * 128;                          // n
  const int NT = K >> 5;

  f32x4 acc[4][4];
  const f32x4 zero = {0.f, 0.f, 0.f, 0.f};
#pragma unroll
  for (int a = 0; a < 4; a++)
#pragma unroll
    for (int b = 0; b < 4; b++) acc[a][b] = zero;

  const int rw = tid >> 2;
  const int sl = (tid & 3) ^ ((tid >> 3) & 3);
  const unsigned short* sW  = W   + (size_t)(nblock + rw) * K + sl * 8;
  const unsigned short* sB0 = Act + (size_t)(mblock + rw)       * K + sl * 8;
  const unsigned short* sB1 = Act + (size_t)(mblock + 128 + rw) * K + sl * 8;

  const int swz = (quad * 8) ^ ((l15 & 6) << 2);

#pragma unroll
  for (int t = 0; t < 2; ++t) {
    unsigned short* d = S + t * 12288 + tid * 8;
    GL2LDS16(sW  + t * 32, d);
    GL2LDS16(sB0 + t * 32, d + 4096);
    GL2LDS16(sB1 + t * 32, d + 8192);
  }
  asm volatile("s_waitcnt vmcnt(3)" ::: "memory");
  __builtin_amdgcn_s_barrier();
  __builtin_amdgcn_sched_barrier(0);

  int bC = 0;
  int bS = 2;
  for (int kt = 0; kt < NT; ++kt) {
    const unsigned short* SA = S + bC * 12288;
    const unsigned short* SB = SA + 4096;

    f16x8 af[4], bf[4];
#pragma unroll
    for (int t4 = 0; t4 < 4; t4++)
      af[t4] = *(const f16x8*)(SA + (wr * 64 + t4 * 16 + l15) * 32 + swz);
#pragma unroll
    for (int t4 = 0; t4 < 4; t4++)
      bf[t4] = *(const f16x8*)(SB + (wc * 64 + t4 * 16 + l15) * 32 + swz);

    if (kt + 2 < NT) {
      const int kb = (kt + 2) * 32;
      unsigned short* d = S + bS * 12288 + tid * 8;
      GL2LDS16(sW  + kb, d);
      GL2LDS16(sB0 + kb, d + 4096);
      GL2LDS16(sB1 + kb, d + 8192);
    }

    __builtin_amdgcn_s_barrier();
    asm volatile("s_waitcnt lgkmcnt(0)" ::: "memory");
    __builtin_amdgcn_sched_barrier(0);
    __builtin_amdgcn_s_setprio(1);
#pragma unroll
    for (int tn = 0; tn < 4; tn++)
#pragma unroll
      for (int tm = 0; tm < 4; tm++)
        acc[tn][tm] = __builtin_amdgcn_mfma_f32_16x16x32_f16(
            af[tn], bf[tm], acc[tn][tm], 0, 0, 0);
    __builtin_amdgcn_s_setprio(0);

    if (kt < NT - 1) {
      if (kt + 2 < NT) asm volatile("s_waitcnt vmcnt(3)" ::: "memory");
      else             asm volatile("s_waitcnt vmcnt(0)" ::: "memory");
      __builtin_amdgcn_s_barrier();
      __builtin_amdgcn_sched_barrier(0);
    }
    bC = bC == 2 ? 0 : bC + 1;
    bS = bS == 2 ? 0 : bS + 1;
  }

  // head epilogue: fp32 logits, n < 257 masked
#pragma unroll
  for (int tn = 0; tn < 4; tn++) {
    const int n = nblock + wr * 64 + tn * 16 + quad * 4;
    if (n < 257) {
#pragma unroll
      for (int tm = 0; tm < 4; tm++) {
        const int token = mblock + wc * 64 + tm * 16 + l15;
        const f32x4 v = acc[tn][tm];
#pragma unroll
        for (int r = 0; r < 4; r++)
          if (n + r < 257) OutF[(size_t)token * 257 + n + r] = v[r];
      }
    }
  }
}

// ---------------------------------------------------------------------------
extern "C" void kernel_launch(void* const* d_in, const int* in_sizes, int n_in,
                              void* d_out, int out_size, void* d_ws,
                              size_t ws_size, hipStream_t stream) {
  const int*   x    = (const int*)d_in[0];
  const float* emb  = (const float*)d_in[1];
  const float* we0  = (const float*)d_in[2];
  const float* we1  = (const float*)d_in[3];
  const float* we2  = (const float*)d_in[4];
  const float* we3  = (const float*)d_in[5];
  const float* we4  = (const float*)d_in[6];
  const float* we5  = (const float*)d_in[7];
  const float* we6  = (const float*)d_in[8];
  const float* we7  = (const float*)d_in[9];
  const float* wlay = (const float*)d_in[10];
  const float* wh   = (const float*)d_in[11];
  float* out = (float*)d_out;

  // workspace layout (~142 MiB)
  char* p = (char*)d_ws;
  auto alloc = [&](size_t bytes) {
    void* r = (void*)p;
    p += (bytes + 255) & ~(size_t)255;
    return r;
  };
  unsigned short* act0 = (unsigned short*)alloc(32768ull * 1024 * 2);
  unsigned short* act1 = (unsigned short*)alloc(32768ull * 1024 * 2);
  unsigned short* E4 = (unsigned short*)alloc(128 * 64 * 2);
  unsigned short* E5 = (unsigned short*)alloc(128 * 128 * 2);
  unsigned short* E6 = (unsigned short*)alloc(256 * 256 * 2);
  unsigned short* E7 = (unsigned short*)alloc(512 * 512 * 2);
  unsigned short* EL = (unsigned short*)alloc(6ull * 1024 * 1024 * 2);
  unsigned short* WH = (unsigned short*)alloc(384 * 1024 * 2);

  // zero the stability-loss slot (d_out is poisoned before every launch)
  hipMemsetAsync(out + 8421376, 0, 4, stream);

  // weight expansion (Hamilton blocks -> real fp16 matrices)
  expand_ham<<<dim3(8192 / 256), 256, 0, stream>>>(we4, E4, 16, 6, 128 * 64);
  expand_ham<<<dim3(16384 / 256), 256, 0, stream>>>(we5, E5, 32, 7, 128 * 128);
  expand_ham<<<dim3(65536 / 256), 256, 0, stream>>>(we6, E6, 64, 8, 256 * 256);
  expand_ham<<<dim3(262144 / 256), 256, 0, stream>>>(we7, E7, 128, 9,
                                                     512 * 512);
  expand_ham6<<<dim3(6 * 1048576 / 256), 256, 0, stream>>>(wlay, EL);
  conv_head<<<dim3(384 * 1024 / 256), 256, 0, stream>>>(wh, WH);

  // embed + expansion steps 0..3 -> act0 [32768][64] fp16
  embed_expand<<<dim3(128), 256, 0, stream>>>(x, emb, we0, we1, we2, we3, act0);

  // expansion steps 4..5 (small K) on the old 128x128 kernel
  gemm_epi0<<<dim3(1, 256), 256, 0, stream>>>(E4, act0, act1, 64, 64, 128);
  gemm_epi0<<<dim3(1, 256), 256, 0, stream>>>(E5, act1, act0, 128, 128, 256);
  // expansion steps 6..7 on the gemm8p family (EPI 0)
  gemm8p<0><<<dim3(2, 128), 512, 0, stream>>>(E6, act0, act1, nullptr, 256,
                                              256, 512);
  gemm8p<0><<<dim3(4, 128), 512, 0, stream>>>(E7, act1, act0, nullptr, 512,
                                              512, 1024);

  // 6 quaternion-linear + normalize layers on the R8 kernel
  unsigned short* a = act0;
  unsigned short* b = act1;
  for (int d = 0; d < 5; d++) {
    gemm8p<1><<<dim3(8, 128), 512, 0, stream>>>(EL + (size_t)d * 1048576, a, b,
                                                nullptr, 1024, 1024, 1024);
    unsigned short* t = a; a = b; b = t;
  }
  gemm8p<2><<<dim3(8, 128), 512, 0, stream>>>(EL + 5ull * 1048576, a, b,
                                              out + 8421376, 1024, 1024, 1024);
  { unsigned short* t = a; a = b; b = t; }

  // head: logits = h @ w_head^T  (WH 384 exact rows; masked stores n<257)
  gemm_head<<<dim3(3, 128), 512, 0, stream>>>(WH, a, out, 1024);
}

// Round 14
// 822.486 us; speedup vs baseline: 1.1341x; 1.1341x over previous
//
#include <hip/hip_runtime.h>

// ---------------------------------------------------------------------------
// H2Q knot kernel: embed -> 8 doubling quaternion expansion steps ->
// 6 quaternion-linear+normalize layers -> vocab head (+ stability loss).
// R19 = byte-exact resubmit of R15 (796.75 us, session best, verified).
// R16 (coop fusion) failed correctness; R17/R18 consolidations regressed via
// rule-#19 co-compilation perturbation of the layer kernel (R18: +40MB
// WRITE/dispatch, MfmaUtil 34->27). This instantiation set {gemm_epi0,
// gemm8p<1,2>, gemm_8ph<0,3>} is the one measured healthy end-to-end.
//  - layers: R8 ring-3 128n x 256m gemm8p, 2 blocks/CU (87.5-89.5 us).
//  - E6/E7 + head: gemm_8ph 256x256 8-phase (de-pressurized staging:
//    2 per-lane base pointers + uniform 64-row stride; WH padded to 512).
//  - front-end: 4-step embed; E4/E5 on gemm_epi0.
// ---------------------------------------------------------------------------

typedef _Float16 f16x8 __attribute__((ext_vector_type(8)));
typedef float    f32x4 __attribute__((ext_vector_type(4)));

#define GL2LDS16(gp, lp) __builtin_amdgcn_global_load_lds(                     \
    (const __attribute__((address_space(1))) void*)(gp),                       \
    (__attribute__((address_space(3))) void*)(lp), 16, 0, 0)

// stage one half-tile (128 rows x 64 k) = 2 glds/thread (gemm_8ph).
// PB = per-lane base (row r8, slot s8 folded in); group g offset = uniform
// multiples of oG = 64*K elements -> folds to scalar addressing.
#define STG(slot, isB, half, PB, kb)                                           \
  do {                                                                         \
    GL2LDS16((PB) + (size_t)(2 * (half)) * oG + (kb),                          \
             S + (slot) * 32768 + (isB) * 16384 + (half) * 8192 + tid * 8);    \
    GL2LDS16((PB) + (size_t)(2 * (half) + 1) * oG + (kb),                      \
             S + (slot) * 32768 + (isB) * 16384 + (half) * 8192 + 4096 +       \
                 tid * 8);                                                     \
  } while (0)

__device__ __forceinline__ unsigned short f2h(float f) {
  union { _Float16 h; unsigned short u; } c;
  c.h = (_Float16)f;                       // RNE
  return c.u;
}
__device__ __forceinline__ float h2f(unsigned short u) {
  union { unsigned short u; _Float16 h; } c;
  c.u = u;
  return (float)c.h;
}

// ---------------------------------------------------------------------------
// Weight expansion: quaternion weights [4][cq][cq] -> real fp16 matrix
// E[n][k], n=4o+a (out), k=4i+b (in), rows >= 4cq zero-padded.
// ---------------------------------------------------------------------------
__global__ __launch_bounds__(256) void expand_ham(
    const float* __restrict__ w, unsigned short* __restrict__ out,
    int cq, int kbits, int total) {
  int id = blockIdx.x * 256 + threadIdx.x;
  if (id >= total) return;
  const int K = 1 << kbits;
  const int n = id >> kbits;
  const int k = id & (K - 1);
  float val = 0.f;
  if (n < 4 * cq) {
    const int o = n >> 2, a = n & 3, i = k >> 2, b = k & 3;
    const int   comp[4][4] = {{0,1,2,3},{1,0,3,2},{2,3,0,1},{3,2,1,0}};
    const float sgn [4][4] = {{1.f,-1.f,-1.f,-1.f},{1.f,1.f,1.f,-1.f},
                              {1.f,-1.f,1.f,1.f},{1.f,1.f,-1.f,1.f}};
    val = sgn[a][b] * w[comp[a][b] * cq * cq + o * cq + i];
  }
  out[id] = f2h(val);
}

// All 6 layer weights (cq=256) in one kernel: w [6][4][256][256] -> E
// [6][1024][1024] fp16.
__global__ __launch_bounds__(256) void expand_ham6(
    const float* __restrict__ w, unsigned short* __restrict__ out) {
  const int id = blockIdx.x * 256 + threadIdx.x;   // 6*1024*1024 threads
  const int d = id >> 20;
  const int r = id & 1048575;
  const int n = r >> 10, k = r & 1023;
  const int o = n >> 2, a = n & 3, i = k >> 2, b = k & 3;
  const int   comp[4][4] = {{0,1,2,3},{1,0,3,2},{2,3,0,1},{3,2,1,0}};
  const float sgn [4][4] = {{1.f,-1.f,-1.f,-1.f},{1.f,1.f,1.f,-1.f},
                            {1.f,-1.f,1.f,1.f},{1.f,1.f,-1.f,1.f}};
  const float val =
      sgn[a][b] * w[d * 262144 + comp[a][b] * 65536 + o * 256 + i];
  out[id] = f2h(val);
}

// Head weights padded to 512 rows (zero-filled) so gemm_8ph needs no clamp.
__global__ __launch_bounds__(256) void conv_head(
    const float* __restrict__ wh, unsigned short* __restrict__ out) {
  int id = blockIdx.x * 256 + threadIdx.x;   // 512*1024 threads
  int v = id >> 10, k = id & 1023;
  out[id] = f2h(v < 257 ? wh[v * 1024 + k] : 0.f);
}

// ---------------------------------------------------------------------------
// Embed + expansion steps 0..3 (cq=1,2,4,8), one token per thread (weights
// wave-uniform -> scalar-cached broadcast loads). Output fp16 [32768][64].
// ---------------------------------------------------------------------------
template <int CQ>
__device__ __forceinline__ void exp_step(float (&q)[16][4],
                                         const float* __restrict__ w) {
  float d[CQ][4];
#pragma unroll
  for (int o = 0; o < CQ; o++) {
    float pr = 0.f, pi = 0.f, pj = 0.f, pk = 0.f;
#pragma unroll
    for (int i = 0; i < CQ; i++) {
      const float wr = w[0 * CQ * CQ + o * CQ + i];
      const float wi = w[1 * CQ * CQ + o * CQ + i];
      const float wj = w[2 * CQ * CQ + o * CQ + i];
      const float wk = w[3 * CQ * CQ + o * CQ + i];
      const float qr = q[i][0], qi = q[i][1], qj = q[i][2], qk = q[i][3];
      pr += wr * qr - wi * qi - wj * qj - wk * qk;
      pi += wi * qr + wr * qi + wk * qj - wj * qk;
      pj += wj * qr - wk * qi + wr * qj + wi * qk;
      pk += wk * qr + wj * qi - wi * qj + wr * qk;
    }
    d[o][0] = tanhf(pr); d[o][1] = tanhf(pi);
    d[o][2] = tanhf(pj); d[o][3] = tanhf(pk);
  }
#pragma unroll
  for (int o = 0; o < CQ; o++)
#pragma unroll
    for (int a = 0; a < 4; a++) {
      const float dd = d[o][a], qq = q[o][a];
      q[o][a]      = qq + dd;
      q[CQ + o][a] = qq - dd;
    }
}

__global__ __launch_bounds__(256) void embed_expand(
    const int* __restrict__ x, const float* __restrict__ emb,
    const float* __restrict__ w0, const float* __restrict__ w1,
    const float* __restrict__ w2, const float* __restrict__ w3,
    unsigned short* __restrict__ out) {
  const int t = blockIdx.x * 256 + threadIdx.x;  // 32768 tokens
  float q[16][4];
  const int v = x[t];
  const float4 e = *(const float4*)(emb + v * 4);
  q[0][0] = e.x; q[0][1] = e.y; q[0][2] = e.z; q[0][3] = e.w;
  exp_step<1>(q, w0);
  exp_step<2>(q, w1);
  exp_step<4>(q, w2);
  exp_step<8>(q, w3);
  ushort4* o4 = (ushort4*)(out + (size_t)t * 64);
#pragma unroll
  for (int c = 0; c < 16; c++) {
    ushort4 u;
    u.x = f2h(q[c][0]); u.y = f2h(q[c][1]);
    u.z = f2h(q[c][2]); u.w = f2h(q[c][3]);
    o4[c] = u;
  }
}

// ---------------------------------------------------------------------------
// Old 128x128 fused GEMM, kept only for small expansion steps E4/E5 (EPI 0).
// ---------------------------------------------------------------------------
__global__ __launch_bounds__(256) void gemm_epi0(
    const unsigned short* __restrict__ W,
    const unsigned short* __restrict__ Act,
    unsigned short* __restrict__ OutB,
    int K, int Nreal, int ldout) {
  __shared__ unsigned short WtL[128 * 32];
  __shared__ unsigned short WtH[128 * 32];
  __shared__ unsigned short AtL[128 * 32];
  __shared__ unsigned short AtH[128 * 32];

  const int tid  = threadIdx.x;
  const int wave = tid >> 6;
  const int lane = tid & 63;
  const int l15  = lane & 15;
  const int quad = lane >> 4;

  const int Gx = gridDim.x;
  const int L  = blockIdx.y * Gx + blockIdx.x;
  const int j  = L & 7;
  const int s  = L >> 3;
  const int nblock = (s % Gx) * 128;               // n (output feature)
  const int mblock = (32 * j + s / Gx) * 128;      // token
  const int wn = (wave & 1) * 64;
  const int wm = (wave >> 1) * 64;

  f32x4 acc[4][4];
  const f32x4 zero = {0.f, 0.f, 0.f, 0.f};
#pragma unroll
  for (int a = 0; a < 4; a++)
#pragma unroll
    for (int b = 0; b < 4; b++) acc[a][b] = zero;

  const int row0 = tid >> 2;
  const int sub  = tid & 3;
  const unsigned short* gW0 = W   + (size_t)(nblock + row0)      * K + sub * 8;
  const unsigned short* gW1 = W   + (size_t)(nblock + row0 + 64) * K + sub * 8;
  const unsigned short* gA0 = Act + (size_t)(mblock + row0)      * K + sub * 8;
  const unsigned short* gA1 = Act + (size_t)(mblock + row0 + 64) * K + sub * 8;
  unsigned short* lWL0 = &WtL[wave * 512];
  unsigned short* lWL1 = &WtL[2048 + wave * 512];
  unsigned short* lWH0 = &WtH[wave * 512];
  unsigned short* lWH1 = &WtH[2048 + wave * 512];
  unsigned short* lAL0 = &AtL[wave * 512];
  unsigned short* lAL1 = &AtL[2048 + wave * 512];
  unsigned short* lAH0 = &AtH[wave * 512];
  unsigned short* lAH1 = &AtH[2048 + wave * 512];

  for (int kb = 0; kb < K; kb += 64) {
    GL2LDS16(gW0 + kb,      lWL0);
    GL2LDS16(gW1 + kb,      lWL1);
    GL2LDS16(gW0 + kb + 32, lWH0);
    GL2LDS16(gW1 + kb + 32, lWH1);
    GL2LDS16(gA0 + kb,      lAL0);
    GL2LDS16(gA1 + kb,      lAL1);
    GL2LDS16(gA0 + kb + 32, lAH0);
    GL2LDS16(gA1 + kb + 32, lAH1);
    __syncthreads();

    {
      f16x8 afr[4], bfr[4];
#pragma unroll
      for (int tn = 0; tn < 4; tn++)
        afr[tn] = *(const f16x8*)&WtL[(wn + tn * 16 + l15) * 32 + quad * 8];
#pragma unroll
      for (int tm = 0; tm < 4; tm++)
        bfr[tm] = *(const f16x8*)&AtL[(wm + tm * 16 + l15) * 32 + quad * 8];
#pragma unroll
      for (int tn = 0; tn < 4; tn++)
#pragma unroll
        for (int tm = 0; tm < 4; tm++)
          acc[tn][tm] = __builtin_amdgcn_mfma_f32_16x16x32_f16(
              afr[tn], bfr[tm], acc[tn][tm], 0, 0, 0);
    }
    {
      f16x8 afr[4], bfr[4];
#pragma unroll
      for (int tn = 0; tn < 4; tn++)
        afr[tn] = *(const f16x8*)&WtH[(wn + tn * 16 + l15) * 32 + quad * 8];
#pragma unroll
      for (int tm = 0; tm < 4; tm++)
        bfr[tm] = *(const f16x8*)&AtH[(wm + tm * 16 + l15) * 32 + quad * 8];
#pragma unroll
      for (int tn = 0; tn < 4; tn++)
#pragma unroll
        for (int tm = 0; tm < 4; tm++)
          acc[tn][tm] = __builtin_amdgcn_mfma_f32_16x16x32_f16(
              afr[tn], bfr[tm], acc[tn][tm], 0, 0, 0);
    }
    __syncthreads();
  }

  // expansion step epilogue
#pragma unroll
  for (int tn = 0; tn < 4; tn++) {
    const int n = nblock + wn + tn * 16 + quad * 4;
    if (n < Nreal) {
#pragma unroll
      for (int tm = 0; tm < 4; tm++) {
        const int token = mblock + wm + tm * 16 + l15;
        const f32x4 v = acc[tn][tm];
        const unsigned short* ip = Act + (size_t)token * K + n;
        const float i0 = h2f(ip[0]), i1 = h2f(ip[1]);
        const float i2 = h2f(ip[2]), i3 = h2f(ip[3]);
        const float d0 = tanhf(v[0]), d1 = tanhf(v[1]);
        const float d2 = tanhf(v[2]), d3 = tanhf(v[3]);
        ushort4 up, um;
        up.x = f2h(i0 + d0); up.y = f2h(i1 + d1);
        up.z = f2h(i2 + d2); up.w = f2h(i3 + d3);
        um.x = f2h(i0 - d0); um.y = f2h(i1 - d1);
        um.z = f2h(i2 - d2); um.w = f2h(i3 - d3);
        *(ushort4*)&OutB[(size_t)token * ldout + n] = up;
        *(ushort4*)&OutB[(size_t)token * ldout + Nreal + n] = um;
      }
    }
  }
}

// ---------------------------------------------------------------------------
// R8 layer GEMM: 128n x 256m, 8 waves (2x4) of 64x64, ring-3 24KB LDS bufs
// (72 KB), launch_bounds(512,4) -> ~60 VGPR -> 2 blocks/CU resident
// (cross-block LDS/MFMA anti-phasing, m114 — best measured: 87.5 us/layer).
// Per K-tile(32): 8 ds_read_b128 + stage kt+2 (3 glds) -> barrier ->
// lgkmcnt(0)+sched_barrier -> setprio'd 16 MFMA -> counted vmcnt(3) ->
// barrier. T2 swizzle: read halfword-off ^((l15&6)<<2), inverse on source
// k-slot. C/D: col=token=lane&15, row=n=(lane>>4)*4+reg.
// EPI: 1 = qnormalize -> fp16 [token][1024]; 2 = EPI1 + stability loss.
// ---------------------------------------------------------------------------
template <int EPI>
__global__ __launch_bounds__(512, 4) void gemm8p(
    const unsigned short* __restrict__ W,
    const unsigned short* __restrict__ Act,
    unsigned short* __restrict__ OutB, float* __restrict__ OutF,
    int K, int NW, int ldout) {
  __shared__ unsigned short S[3 * 12288];   // ring-3: [W 4096 | B 8192] ush
  __shared__ float lsum[8];

  const int tid  = threadIdx.x;
  const int wave = tid >> 6;
  const int lane = tid & 63;
  const int l15  = lane & 15;
  const int quad = lane >> 4;
  const int wr   = wave >> 2;          // 0..1  n half (64 rows)
  const int wc   = wave & 3;           // 0..3  token quarter (64 cols)

  // XCD swizzle: xcd j = L%8 owns m-tiles [j*Gy/8, (j+1)*Gy/8), n fastest
  const int Gx = gridDim.x;
  const int L  = blockIdx.y * Gx + blockIdx.x;
  const int j  = L & 7;
  const int s  = L >> 3;
  const int mblock = (j * (gridDim.y >> 3) + s / Gx) * 256;   // token
  const int nblock = (s % Gx) * 128;                          // n
  const int NT = K >> 5;               // K-tiles of 32

  f32x4 acc[4][4];
  const f32x4 zero = {0.f, 0.f, 0.f, 0.f};
#pragma unroll
  for (int a = 0; a < 4; a++)
#pragma unroll
    for (int b = 0; b < 4; b++) acc[a][b] = zero;

  // Staging: thread t -> row t>>2, 16B slot t&3 of the 64B k-row.
  // Source k-slot inverse-swizzled: sl = (t&3) ^ ((row&6)>>1).
  const int rw = tid >> 2;                       // 0..127
  const int sl = (tid & 3) ^ ((tid >> 3) & 3);
  const int wrow = nblock + rw;
  const int cwr  = wrow < NW ? wrow : NW - 1;    // clamp (exact fit at all
                                                 // current call sites)
  const unsigned short* sW  = W   + (size_t)cwr * K + sl * 8;
  const unsigned short* sB0 = Act + (size_t)(mblock + rw)       * K + sl * 8;
  const unsigned short* sB1 = Act + (size_t)(mblock + 128 + rw) * K + sl * 8;

  // Read-side swizzle: rows are X*16+l15 -> row&6 == l15&6, constant per lane
  const int swz = (quad * 8) ^ ((l15 & 6) << 2);   // halfword offset XOR

  // prologue: stage tiles 0,1 into bufs 0,1 (3 glds each)
#pragma unroll
  for (int t = 0; t < 2; ++t) {
    unsigned short* d = S + t * 12288 + tid * 8;
    GL2LDS16(sW  + t * 32, d);
    GL2LDS16(sB0 + t * 32, d + 4096);
    GL2LDS16(sB1 + t * 32, d + 8192);
  }
  asm volatile("s_waitcnt vmcnt(3)" ::: "memory");   // tile 0 landed
  __builtin_amdgcn_s_barrier();
  __builtin_amdgcn_sched_barrier(0);

  int bC = 0;   // buffer holding tile kt
  int bS = 2;   // buffer receiving tile kt+2
  for (int kt = 0; kt < NT; ++kt) {
    const unsigned short* SA = S + bC * 12288;
    const unsigned short* SB = SA + 4096;

    f16x8 af[4], bf[4];
#pragma unroll
    for (int t4 = 0; t4 < 4; t4++)
      af[t4] = *(const f16x8*)(SA + (wr * 64 + t4 * 16 + l15) * 32 + swz);
#pragma unroll
    for (int t4 = 0; t4 < 4; t4++)
      bf[t4] = *(const f16x8*)(SB + (wc * 64 + t4 * 16 + l15) * 32 + swz);

    // stage tile kt+2 into buf bS (read last at tile kt-1; reads drained
    // before the previous boundary barrier)
    if (kt + 2 < NT) {
      const int kb = (kt + 2) * 32;
      unsigned short* d = S + bS * 12288 + tid * 8;
      GL2LDS16(sW  + kb, d);
      GL2LDS16(sB0 + kb, d + 4096);
      GL2LDS16(sB1 + kb, d + 8192);
    }

    __builtin_amdgcn_s_barrier();
    asm volatile("s_waitcnt lgkmcnt(0)" ::: "memory");
    __builtin_amdgcn_sched_barrier(0);
    __builtin_amdgcn_s_setprio(1);
#pragma unroll
    for (int tn = 0; tn < 4; tn++)
#pragma unroll
      for (int tm = 0; tm < 4; tm++)
        acc[tn][tm] = __builtin_amdgcn_mfma_f32_16x16x32_f16(
            af[tn], bf[tm], acc[tn][tm], 0, 0, 0);
    __builtin_amdgcn_s_setprio(0);

    // boundary: tile kt+1 must have landed; keep kt+2 in flight (counted)
    if (kt < NT - 1) {
      if (kt + 2 < NT) asm volatile("s_waitcnt vmcnt(3)" ::: "memory");
      else             asm volatile("s_waitcnt vmcnt(0)" ::: "memory");
      __builtin_amdgcn_s_barrier();
      __builtin_amdgcn_sched_barrier(0);
    }
    bC = bC == 2 ? 0 : bC + 1;
    bS = bS == 2 ? 0 : bS + 1;
  }

  {
    float loss = 0.f;
#pragma unroll
    for (int tn = 0; tn < 4; tn++) {
      const int n = nblock + wr * 64 + tn * 16 + quad * 4;
#pragma unroll
      for (int tm = 0; tm < 4; tm++) {
        const int token = mblock + wc * 64 + tm * 16 + l15;
        const f32x4 v = acc[tn][tm];
        const float nrm =
            sqrtf(v[0] * v[0] + v[1] * v[1] + v[2] * v[2] + v[3] * v[3]);
        const float inv = 1.f / (nrm + 1e-8f);
        ushort4 u;
        u.x = f2h(v[0] * inv); u.y = f2h(v[1] * inv);
        u.z = f2h(v[2] * inv); u.w = f2h(v[3] * inv);
        *(ushort4*)&OutB[(size_t)token * 1024 + n] = u;
        if constexpr (EPI == 2) loss += fabsf(v[0] * inv);
      }
    }
    if constexpr (EPI == 2) {
#pragma unroll
      for (int off = 32; off > 0; off >>= 1) loss += __shfl_down(loss, off);
      if (lane == 0) lsum[wave] = loss;
      __syncthreads();
      if (tid == 0) {
        float t = 0.f;
#pragma unroll
        for (int w8 = 0; w8 < 8; w8++) t += lsum[w8];
        atomicAdd(OutF, t * (1.f / 8388608.f));
      }
    }
  }
}

// ---------------------------------------------------------------------------
// 8-phase 256x256 GEMM (E6/E7 expansion + head). BK=64, dbuf-2 slots
// (128 KB LDS, 8 waves 2x4, per-wave C 128x64). 8 phases/iter; B-frags held
// in regs across 4 quadrant phases; one half-tile glds stage per phase;
// vmcnt(4) gates at phase 3/7 only. Swizzle: read 16B-slot
// (ksub*4+quad)^(row&7); inverse on glds source slot.
// Pressure fix: staging addresses = 2 per-lane bases (pWb/pBb) + uniform
// group stride oG (8 per-lane pointers + clamp caused a spill at the
// 256-reg edge under co-compilation perturbation, R14).
// W must have >= nblock+256 rows at every call site (WH padded to 512).
// EPI: 0 = expansion step; 3 = head (fp32, n<257 masked).
// Requires K multiple of 128 (call sites 256/512/1024).
// ---------------------------------------------------------------------------
template <int EPI>
__global__ __launch_bounds__(512, 2) void gemm_8ph(
    const unsigned short* __restrict__ W,
    const unsigned short* __restrict__ Act,
    unsigned short* __restrict__ OutB, float* __restrict__ OutF,
    int K, int NW, int ldout) {
  __shared__ unsigned short S[65536];   // 2 slots x (A 16384 | B 16384) hw

  const int tid  = threadIdx.x;
  const int wave = tid >> 6;
  const int lane = tid & 63;
  const int l15  = lane & 15;
  const int quad = lane >> 4;
  const int wr   = wave >> 2;          // 0..1  n half (128 rows)
  const int wc   = wave & 3;           // 0..3  token quarter (64 cols)

  const int Gx = gridDim.x;
  const int L  = blockIdx.y * Gx + blockIdx.x;
  const int j  = L & 7;
  const int s  = L >> 3;
  const int mblock = (j * (gridDim.y >> 3) + s / Gx) * 256;   // token
  const int nblock = (s % Gx) * 256;                          // n
  const int NI = K >> 7;               // iters of 128 k (2 K-steps of 64)

  f32x4 acc[8][4];
  const f32x4 zero = {0.f, 0.f, 0.f, 0.f};
#pragma unroll
  for (int a = 0; a < 8; a++)
#pragma unroll
    for (int b = 0; b < 4; b++) acc[a][b] = zero;

  // Staging: thread covers row r8 = tid>>3 of each 64-row group; source
  // 16B-slot inverse-swizzled s8 = (tid&7)^(r8&7). Group g (0..3) of W/B
  // starts at uniform offset g*oG from the per-lane base.
  const int r8 = tid >> 3;
  const int s8 = (tid & 7) ^ (r8 & 7);
  const size_t oG = (size_t)64 * K;    // 64-row group stride (elements)
  const unsigned short* pWb = W   + (size_t)nblock * K + r8 * K + s8 * 8;
  const unsigned short* pBb = Act + (size_t)mblock * K + r8 * K + s8 * 8;

  const int lrow = l15 * 64;                          // hw
  const int ksw0 = ((quad)     ^ (l15 & 7)) * 8;      // ksub 0 16B-slot
  const int ksw1 = ((4 + quad) ^ (l15 & 7)) * 8;      // ksub 1

  // prologue: A(0), B(0) -> slot0; B(1) -> slot1
  STG(0, 0, 0, pWb, 0);  STG(0, 0, 1, pWb, 0);
  STG(0, 1, 0, pBb, 0);  STG(0, 1, 1, pBb, 0);
  STG(1, 1, 0, pBb, 64); STG(1, 1, 1, pBb, 64);
  asm volatile("s_waitcnt vmcnt(4)" ::: "memory");
  __builtin_amdgcn_s_barrier();
  __builtin_amdgcn_sched_barrier(0);

  f16x8 bfr[4][2];
  for (int i = 0; i < NI; ++i) {
    const bool nl = (i < NI - 1);
    const int kA1 = (2 * i + 1) * 64;      // A(2i+1) -> slot1
    const int k2  = (2 * i + 2) * 64;      // -> slot0
    const int k3  = (2 * i + 3) * 64;      // -> slot1
#pragma unroll
    for (int p = 0; p < 8; ++p) {
      const int q  = p & 3;
      const int sb = (p >> 2) * 32768;
      if (q == 0) {
#pragma unroll
        for (int c = 0; c < 4; ++c) {
          const unsigned short* bp = S + sb + 16384 + (wc * 64 + c * 16) * 64
                                       + lrow;
          bfr[c][0] = *(const f16x8*)(bp + ksw0);
          bfr[c][1] = *(const f16x8*)(bp + ksw1);
        }
      }
      f16x8 af[2][2];
#pragma unroll
      for (int f = 0; f < 2; ++f) {
        const unsigned short* ap = S + sb + (wr * 128 + q * 32 + f * 16) * 64
                                     + lrow;
        af[f][0] = *(const f16x8*)(ap + ksw0);
        af[f][1] = *(const f16x8*)(ap + ksw1);
      }
      if      (p == 0) { STG(1, 0, 0, pWb, kA1); }
      else if (p == 1) { STG(1, 0, 1, pWb, kA1); }
      else if (p == 2) { if (nl) STG(0, 1, 0, pBb, k2); }
      else if (p == 3) { if (nl) STG(0, 1, 1, pBb, k2); }
      else if (p == 4) { if (nl) STG(0, 0, 0, pWb, k2); }
      else if (p == 5) { if (nl) STG(0, 0, 1, pWb, k2); }
      else if (p == 6) { if (nl) STG(1, 1, 0, pBb, k3); }
      else             { if (nl) STG(1, 1, 1, pBb, k3); }

      __builtin_amdgcn_s_barrier();
      asm volatile("s_waitcnt lgkmcnt(0)" ::: "memory");
      __builtin_amdgcn_sched_barrier(0);
      __builtin_amdgcn_s_setprio(1);
#pragma unroll
      for (int f = 0; f < 2; ++f)
#pragma unroll
        for (int c = 0; c < 4; ++c) {
          acc[q * 2 + f][c] = __builtin_amdgcn_mfma_f32_16x16x32_f16(
              af[f][0], bfr[c][0], acc[q * 2 + f][c], 0, 0, 0);
          acc[q * 2 + f][c] = __builtin_amdgcn_mfma_f32_16x16x32_f16(
              af[f][1], bfr[c][1], acc[q * 2 + f][c], 0, 0, 0);
        }
      __builtin_amdgcn_s_setprio(0);

      if (p == 3) {
        if (nl) asm volatile("s_waitcnt vmcnt(4)" ::: "memory");
        else    asm volatile("s_waitcnt vmcnt(0)" ::: "memory");
        __builtin_amdgcn_s_barrier();
        __builtin_amdgcn_sched_barrier(0);
      } else if (p == 7) {
        if (nl) {
          asm volatile("s_waitcnt vmcnt(4)" ::: "memory");
          __builtin_amdgcn_s_barrier();
          __builtin_amdgcn_sched_barrier(0);
        }
      } else {
        __builtin_amdgcn_s_barrier();
      }
    }
  }

  if constexpr (EPI == 0) {
#pragma unroll
    for (int tn = 0; tn < 8; tn++) {
      const int n = nblock + wr * 128 + tn * 16 + quad * 4;
#pragma unroll
      for (int tm = 0; tm < 4; tm++) {
        const int token = mblock + wc * 64 + tm * 16 + l15;
        const f32x4 v = acc[tn][tm];
        const unsigned short* ip = Act + (size_t)token * K + n;
        const float i0 = h2f(ip[0]), i1 = h2f(ip[1]);
        const float i2 = h2f(ip[2]), i3 = h2f(ip[3]);
        const float d0 = tanhf(v[0]), d1 = tanhf(v[1]);
        const float d2 = tanhf(v[2]), d3 = tanhf(v[3]);
        ushort4 up, um;
        up.x = f2h(i0 + d0); up.y = f2h(i1 + d1);
        up.z = f2h(i2 + d2); up.w = f2h(i3 + d3);
        um.x = f2h(i0 - d0); um.y = f2h(i1 - d1);
        um.z = f2h(i2 - d2); um.w = f2h(i3 - d3);
        *(ushort4*)&OutB[(size_t)token * ldout + n] = up;
        *(ushort4*)&OutB[(size_t)token * ldout + NW + n] = um;
      }
    }
  } else {  // EPI == 3 : head
#pragma unroll
    for (int tn = 0; tn < 8; tn++) {
      const int n = nblock + wr * 128 + tn * 16 + quad * 4;
      if (n < 257) {
#pragma unroll
        for (int tm = 0; tm < 4; tm++) {
          const int token = mblock + wc * 64 + tm * 16 + l15;
          const f32x4 v = acc[tn][tm];
#pragma unroll
          for (int r = 0; r < 4; r++)
            if (n + r < 257) OutF[(size_t)token * 257 + n + r] = v[r];
        }
      }
    }
  }
}

// ---------------------------------------------------------------------------
extern "C" void kernel_launch(void* const* d_in, const int* in_sizes, int n_in,
                              void* d_out, int out_size, void* d_ws,
                              size_t ws_size, hipStream_t stream) {
  const int*   x    = (const int*)d_in[0];
  const float* emb  = (const float*)d_in[1];
  const float* we0  = (const float*)d_in[2];
  const float* we1  = (const float*)d_in[3];
  const float* we2  = (const float*)d_in[4];
  const float* we3  = (const float*)d_in[5];
  const float* we4  = (const float*)d_in[6];
  const float* we5  = (const float*)d_in[7];
  const float* we6  = (const float*)d_in[8];
  const float* we7  = (const float*)d_in[9];
  const float* wlay = (const float*)d_in[10];
  const float* wh   = (const float*)d_in[11];
  float* out = (float*)d_out;

  // workspace layout (~142 MiB)
  char* p = (char*)d_ws;
  auto alloc = [&](size_t bytes) {
    void* r = (void*)p;
    p += (bytes + 255) & ~(size_t)255;
    return r;
  };
  unsigned short* act0 = (unsigned short*)alloc(32768ull * 1024 * 2);
  unsigned short* act1 = (unsigned short*)alloc(32768ull * 1024 * 2);
  unsigned short* E4 = (unsigned short*)alloc(128 * 64 * 2);
  unsigned short* E5 = (unsigned short*)alloc(128 * 128 * 2);
  unsigned short* E6 = (unsigned short*)alloc(256 * 256 * 2);
  unsigned short* E7 = (unsigned short*)alloc(512 * 512 * 2);
  unsigned short* EL = (unsigned short*)alloc(6ull * 1024 * 1024 * 2);
  unsigned short* WH = (unsigned short*)alloc(512 * 1024 * 2);

  // zero the stability-loss slot (d_out is poisoned before every launch)
  hipMemsetAsync(out + 8421376, 0, 4, stream);

  // weight expansion (Hamilton blocks -> real fp16 matrices)
  expand_ham<<<dim3(8192 / 256), 256, 0, stream>>>(we4, E4, 16, 6, 128 * 64);
  expand_ham<<<dim3(16384 / 256), 256, 0, stream>>>(we5, E5, 32, 7, 128 * 128);
  expand_ham<<<dim3(65536 / 256), 256, 0, stream>>>(we6, E6, 64, 8, 256 * 256);
  expand_ham<<<dim3(262144 / 256), 256, 0, stream>>>(we7, E7, 128, 9,
                                                     512 * 512);
  expand_ham6<<<dim3(6 * 1048576 / 256), 256, 0, stream>>>(wlay, EL);
  conv_head<<<dim3(512 * 1024 / 256), 256, 0, stream>>>(wh, WH);

  // embed + expansion steps 0..3 -> act0 [32768][64] fp16
  embed_expand<<<dim3(128), 256, 0, stream>>>(x, emb, we0, we1, we2, we3, act0);

  // expansion steps 4..5 (small K) on the old 128x128 kernel
  gemm_epi0<<<dim3(1, 256), 256, 0, stream>>>(E4, act0, act1, 64, 64, 128);
  gemm_epi0<<<dim3(1, 256), 256, 0, stream>>>(E5, act1, act0, 128, 128, 256);
  // expansion steps 6..7 on the 8-phase kernel (EPI 0)
  gemm_8ph<0><<<dim3(1, 128), 512, 0, stream>>>(E6, act0, act1, nullptr, 256,
                                                256, 512);
  gemm_8ph<0><<<dim3(2, 128), 512, 0, stream>>>(E7, act1, act0, nullptr, 512,
                                                512, 1024);

  // 6 quaternion-linear + normalize layers on the R8 kernel
  unsigned short* a = act0;
  unsigned short* b = act1;
  for (int d = 0; d < 5; d++) {
    gemm8p<1><<<dim3(8, 128), 512, 0, stream>>>(EL + (size_t)d * 1048576, a, b,
                                                nullptr, 1024, 1024, 1024);
    unsigned short* t = a; a = b; b = t;
  }
  gemm8p<2><<<dim3(8, 128), 512, 0, stream>>>(EL + 5ull * 1048576, a, b,
                                              out + 8421376, 1024, 1024, 1024);
  { unsigned short* t = a; a = b; b = t; }

  // head: logits = h @ w_head^T  (WH zero-padded to 512 rows -> 2 exact
  // 256-row n-tiles; masked stores n<257)
  gemm_8ph<3><<<dim3(2, 128), 512, 0, stream>>>(WH, a, nullptr, out, 1024, 0,
                                                0);
}

// Round 16
// 781.951 us; speedup vs baseline: 1.1929x; 1.0518x over previous
//
#include <hip/hip_runtime.h>

// ---------------------------------------------------------------------------
// H2Q knot kernel: embed -> 8 doubling quaternion expansion steps ->
// 6 quaternion-linear+normalize layers -> vocab head (+ stability loss).
// R21 = byte-exact resubmit of R15/R19/R20 (best verified: 796.75 us;
// repeat draw 822.5 us -> noise band +/-1.5-3% on identical source; R20's
// bench was an infra failure, no kernel signal).
// Convergence rationale: (1) any source change re-rolls co-compilation
// codegen (rule #19) with measured tail risk +110..+210 us (R14/R18) for
// sub-noise upside; (2) all >noise levers closed: 5 schedule families
// plateau 87-93 us/layer, coop fusion fails under graph capture (G9/G16),
// fp8 fails error arithmetic (e4m3 ~6% rel/operand -> ~17% direction error
// over 6 normalize-coupled layers >> 0.0389 threshold); (3) structural
// ceiling: fp16-MFMA layer GEMM at ~34% MfmaUtil, residual is latency/sync
// dead time that plain-HIP scheduling cannot remove on this harness.
//  - layers: R8 ring-3 128n x 256m gemm8p, 2 blocks/CU (87.5-89.5 us).
//  - E6/E7 + head: gemm_8ph 256x256 8-phase (de-pressurized staging:
//    2 per-lane base pointers + uniform 64-row stride; WH padded to 512).
//  - front-end: 4-step embed; E4/E5 on gemm_epi0.
// ---------------------------------------------------------------------------

typedef _Float16 f16x8 __attribute__((ext_vector_type(8)));
typedef float    f32x4 __attribute__((ext_vector_type(4)));

#define GL2LDS16(gp, lp) __builtin_amdgcn_global_load_lds(                     \
    (const __attribute__((address_space(1))) void*)(gp),                       \
    (__attribute__((address_space(3))) void*)(lp), 16, 0, 0)

// stage one half-tile (128 rows x 64 k) = 2 glds/thread (gemm_8ph).
// PB = per-lane base (row r8, slot s8 folded in); group g offset = uniform
// multiples of oG = 64*K elements -> folds to scalar addressing.
#define STG(slot, isB, half, PB, kb)                                           \
  do {                                                                         \
    GL2LDS16((PB) + (size_t)(2 * (half)) * oG + (kb),                          \
             S + (slot) * 32768 + (isB) * 16384 + (half) * 8192 + tid * 8);    \
    GL2LDS16((PB) + (size_t)(2 * (half) + 1) * oG + (kb),                      \
             S + (slot) * 32768 + (isB) * 16384 + (half) * 8192 + 4096 +       \
                 tid * 8);                                                     \
  } while (0)

__device__ __forceinline__ unsigned short f2h(float f) {
  union { _Float16 h; unsigned short u; } c;
  c.h = (_Float16)f;                       // RNE
  return c.u;
}
__device__ __forceinline__ float h2f(unsigned short u) {
  union { unsigned short u; _Float16 h; } c;
  c.u = u;
  return (float)c.h;
}

// ---------------------------------------------------------------------------
// Weight expansion: quaternion weights [4][cq][cq] -> real fp16 matrix
// E[n][k], n=4o+a (out), k=4i+b (in), rows >= 4cq zero-padded.
// ---------------------------------------------------------------------------
__global__ __launch_bounds__(256) void expand_ham(
    const float* __restrict__ w, unsigned short* __restrict__ out,
    int cq, int kbits, int total) {
  int id = blockIdx.x * 256 + threadIdx.x;
  if (id >= total) return;
  const int K = 1 << kbits;
  const int n = id >> kbits;
  const int k = id & (K - 1);
  float val = 0.f;
  if (n < 4 * cq) {
    const int o = n >> 2, a = n & 3, i = k >> 2, b = k & 3;
    const int   comp[4][4] = {{0,1,2,3},{1,0,3,2},{2,3,0,1},{3,2,1,0}};
    const float sgn [4][4] = {{1.f,-1.f,-1.f,-1.f},{1.f,1.f,1.f,-1.f},
                              {1.f,-1.f,1.f,1.f},{1.f,1.f,-1.f,1.f}};
    val = sgn[a][b] * w[comp[a][b] * cq * cq + o * cq + i];
  }
  out[id] = f2h(val);
}

// All 6 layer weights (cq=256) in one kernel: w [6][4][256][256] -> E
// [6][1024][1024] fp16.
__global__ __launch_bounds__(256) void expand_ham6(
    const float* __restrict__ w, unsigned short* __restrict__ out) {
  const int id = blockIdx.x * 256 + threadIdx.x;   // 6*1024*1024 threads
  const int d = id >> 20;
  const int r = id & 1048575;
  const int n = r >> 10, k = r & 1023;
  const int o = n >> 2, a = n & 3, i = k >> 2, b = k & 3;
  const int   comp[4][4] = {{0,1,2,3},{1,0,3,2},{2,3,0,1},{3,2,1,0}};
  const float sgn [4][4] = {{1.f,-1.f,-1.f,-1.f},{1.f,1.f,1.f,-1.f},
                            {1.f,-1.f,1.f,1.f},{1.f,1.f,-1.f,1.f}};
  const float val =
      sgn[a][b] * w[d * 262144 + comp[a][b] * 65536 + o * 256 + i];
  out[id] = f2h(val);
}

// Head weights padded to 512 rows (zero-filled) so gemm_8ph needs no clamp.
__global__ __launch_bounds__(256) void conv_head(
    const float* __restrict__ wh, unsigned short* __restrict__ out) {
  int id = blockIdx.x * 256 + threadIdx.x;   // 512*1024 threads
  int v = id >> 10, k = id & 1023;
  out[id] = f2h(v < 257 ? wh[v * 1024 + k] : 0.f);
}

// ---------------------------------------------------------------------------
// Embed + expansion steps 0..3 (cq=1,2,4,8), one token per thread (weights
// wave-uniform -> scalar-cached broadcast loads). Output fp16 [32768][64].
// ---------------------------------------------------------------------------
template <int CQ>
__device__ __forceinline__ void exp_step(float (&q)[16][4],
                                         const float* __restrict__ w) {
  float d[CQ][4];
#pragma unroll
  for (int o = 0; o < CQ; o++) {
    float pr = 0.f, pi = 0.f, pj = 0.f, pk = 0.f;
#pragma unroll
    for (int i = 0; i < CQ; i++) {
      const float wr = w[0 * CQ * CQ + o * CQ + i];
      const float wi = w[1 * CQ * CQ + o * CQ + i];
      const float wj = w[2 * CQ * CQ + o * CQ + i];
      const float wk = w[3 * CQ * CQ + o * CQ + i];
      const float qr = q[i][0], qi = q[i][1], qj = q[i][2], qk = q[i][3];
      pr += wr * qr - wi * qi - wj * qj - wk * qk;
      pi += wi * qr + wr * qi + wk * qj - wj * qk;
      pj += wj * qr - wk * qi + wr * qj + wi * qk;
      pk += wk * qr + wj * qi - wi * qj + wr * qk;
    }
    d[o][0] = tanhf(pr); d[o][1] = tanhf(pi);
    d[o][2] = tanhf(pj); d[o][3] = tanhf(pk);
  }
#pragma unroll
  for (int o = 0; o < CQ; o++)
#pragma unroll
    for (int a = 0; a < 4; a++) {
      const float dd = d[o][a], qq = q[o][a];
      q[o][a]      = qq + dd;
      q[CQ + o][a] = qq - dd;
    }
}

__global__ __launch_bounds__(256) void embed_expand(
    const int* __restrict__ x, const float* __restrict__ emb,
    const float* __restrict__ w0, const float* __restrict__ w1,
    const float* __restrict__ w2, const float* __restrict__ w3,
    unsigned short* __restrict__ out) {
  const int t = blockIdx.x * 256 + threadIdx.x;  // 32768 tokens
  float q[16][4];
  const int v = x[t];
  const float4 e = *(const float4*)(emb + v * 4);
  q[0][0] = e.x; q[0][1] = e.y; q[0][2] = e.z; q[0][3] = e.w;
  exp_step<1>(q, w0);
  exp_step<2>(q, w1);
  exp_step<4>(q, w2);
  exp_step<8>(q, w3);
  ushort4* o4 = (ushort4*)(out + (size_t)t * 64);
#pragma unroll
  for (int c = 0; c < 16; c++) {
    ushort4 u;
    u.x = f2h(q[c][0]); u.y = f2h(q[c][1]);
    u.z = f2h(q[c][2]); u.w = f2h(q[c][3]);
    o4[c] = u;
  }
}

// ---------------------------------------------------------------------------
// Old 128x128 fused GEMM, kept only for small expansion steps E4/E5 (EPI 0).
// ---------------------------------------------------------------------------
__global__ __launch_bounds__(256) void gemm_epi0(
    const unsigned short* __restrict__ W,
    const unsigned short* __restrict__ Act,
    unsigned short* __restrict__ OutB,
    int K, int Nreal, int ldout) {
  __shared__ unsigned short WtL[128 * 32];
  __shared__ unsigned short WtH[128 * 32];
  __shared__ unsigned short AtL[128 * 32];
  __shared__ unsigned short AtH[128 * 32];

  const int tid  = threadIdx.x;
  const int wave = tid >> 6;
  const int lane = tid & 63;
  const int l15  = lane & 15;
  const int quad = lane >> 4;

  const int Gx = gridDim.x;
  const int L  = blockIdx.y * Gx + blockIdx.x;
  const int j  = L & 7;
  const int s  = L >> 3;
  const int nblock = (s % Gx) * 128;               // n (output feature)
  const int mblock = (32 * j + s / Gx) * 128;      // token
  const int wn = (wave & 1) * 64;
  const int wm = (wave >> 1) * 64;

  f32x4 acc[4][4];
  const f32x4 zero = {0.f, 0.f, 0.f, 0.f};
#pragma unroll
  for (int a = 0; a < 4; a++)
#pragma unroll
    for (int b = 0; b < 4; b++) acc[a][b] = zero;

  const int row0 = tid >> 2;
  const int sub  = tid & 3;
  const unsigned short* gW0 = W   + (size_t)(nblock + row0)      * K + sub * 8;
  const unsigned short* gW1 = W   + (size_t)(nblock + row0 + 64) * K + sub * 8;
  const unsigned short* gA0 = Act + (size_t)(mblock + row0)      * K + sub * 8;
  const unsigned short* gA1 = Act + (size_t)(mblock + row0 + 64) * K + sub * 8;
  unsigned short* lWL0 = &WtL[wave * 512];
  unsigned short* lWL1 = &WtL[2048 + wave * 512];
  unsigned short* lWH0 = &WtH[wave * 512];
  unsigned short* lWH1 = &WtH[2048 + wave * 512];
  unsigned short* lAL0 = &AtL[wave * 512];
  unsigned short* lAL1 = &AtL[2048 + wave * 512];
  unsigned short* lAH0 = &AtH[wave * 512];
  unsigned short* lAH1 = &AtH[2048 + wave * 512];

  for (int kb = 0; kb < K; kb += 64) {
    GL2LDS16(gW0 + kb,      lWL0);
    GL2LDS16(gW1 + kb,      lWL1);
    GL2LDS16(gW0 + kb + 32, lWH0);
    GL2LDS16(gW1 + kb + 32, lWH1);
    GL2LDS16(gA0 + kb,      lAL0);
    GL2LDS16(gA1 + kb,      lAL1);
    GL2LDS16(gA0 + kb + 32, lAH0);
    GL2LDS16(gA1 + kb + 32, lAH1);
    __syncthreads();

    {
      f16x8 afr[4], bfr[4];
#pragma unroll
      for (int tn = 0; tn < 4; tn++)
        afr[tn] = *(const f16x8*)&WtL[(wn + tn * 16 + l15) * 32 + quad * 8];
#pragma unroll
      for (int tm = 0; tm < 4; tm++)
        bfr[tm] = *(const f16x8*)&AtL[(wm + tm * 16 + l15) * 32 + quad * 8];
#pragma unroll
      for (int tn = 0; tn < 4; tn++)
#pragma unroll
        for (int tm = 0; tm < 4; tm++)
          acc[tn][tm] = __builtin_amdgcn_mfma_f32_16x16x32_f16(
              afr[tn], bfr[tm], acc[tn][tm], 0, 0, 0);
    }
    {
      f16x8 afr[4], bfr[4];
#pragma unroll
      for (int tn = 0; tn < 4; tn++)
        afr[tn] = *(const f16x8*)&WtH[(wn + tn * 16 + l15) * 32 + quad * 8];
#pragma unroll
      for (int tm = 0; tm < 4; tm++)
        bfr[tm] = *(const f16x8*)&AtH[(wm + tm * 16 + l15) * 32 + quad * 8];
#pragma unroll
      for (int tn = 0; tn < 4; tn++)
#pragma unroll
        for (int tm = 0; tm < 4; tm++)
          acc[tn][tm] = __builtin_amdgcn_mfma_f32_16x16x32_f16(
              afr[tn], bfr[tm], acc[tn][tm], 0, 0, 0);
    }
    __syncthreads();
  }

  // expansion step epilogue
#pragma unroll
  for (int tn = 0; tn < 4; tn++) {
    const int n = nblock + wn + tn * 16 + quad * 4;
    if (n < Nreal) {
#pragma unroll
      for (int tm = 0; tm < 4; tm++) {
        const int token = mblock + wm + tm * 16 + l15;
        const f32x4 v = acc[tn][tm];
        const unsigned short* ip = Act + (size_t)token * K + n;
        const float i0 = h2f(ip[0]), i1 = h2f(ip[1]);
        const float i2 = h2f(ip[2]), i3 = h2f(ip[3]);
        const float d0 = tanhf(v[0]), d1 = tanhf(v[1]);
        const float d2 = tanhf(v[2]), d3 = tanhf(v[3]);
        ushort4 up, um;
        up.x = f2h(i0 + d0); up.y = f2h(i1 + d1);
        up.z = f2h(i2 + d2); up.w = f2h(i3 + d3);
        um.x = f2h(i0 - d0); um.y = f2h(i1 - d1);
        um.z = f2h(i2 - d2); um.w = f2h(i3 - d3);
        *(ushort4*)&OutB[(size_t)token * ldout + n] = up;
        *(ushort4*)&OutB[(size_t)token * ldout + Nreal + n] = um;
      }
    }
  }
}

// ---------------------------------------------------------------------------
// R8 layer GEMM: 128n x 256m, 8 waves (2x4) of 64x64, ring-3 24KB LDS bufs
// (72 KB), launch_bounds(512,4) -> ~60 VGPR -> 2 blocks/CU resident
// (cross-block LDS/MFMA anti-phasing, m114 — best measured: 87.5 us/layer).
// Per K-tile(32): 8 ds_read_b128 + stage kt+2 (3 glds) -> barrier ->
// lgkmcnt(0)+sched_barrier -> setprio'd 16 MFMA -> counted vmcnt(3) ->
// barrier. T2 swizzle: read halfword-off ^((l15&6)<<2), inverse on source
// k-slot. C/D: col=token=lane&15, row=n=(lane>>4)*4+reg.
// EPI: 1 = qnormalize -> fp16 [token][1024]; 2 = EPI1 + stability loss.
// ---------------------------------------------------------------------------
template <int EPI>
__global__ __launch_bounds__(512, 4) void gemm8p(
    const unsigned short* __restrict__ W,
    const unsigned short* __restrict__ Act,
    unsigned short* __restrict__ OutB, float* __restrict__ OutF,
    int K, int NW, int ldout) {
  __shared__ unsigned short S[3 * 12288];   // ring-3: [W 4096 | B 8192] ush
  __shared__ float lsum[8];

  const int tid  = threadIdx.x;
  const int wave = tid >> 6;
  const int lane = tid & 63;
  const int l15  = lane & 15;
  const int quad = lane >> 4;
  const int wr   = wave >> 2;          // 0..1  n half (64 rows)
  const int wc   = wave & 3;           // 0..3  token quarter (64 cols)

  // XCD swizzle: xcd j = L%8 owns m-tiles [j*Gy/8, (j+1)*Gy/8), n fastest
  const int Gx = gridDim.x;
  const int L  = blockIdx.y * Gx + blockIdx.x;
  const int j  = L & 7;
  const int s  = L >> 3;
  const int mblock = (j * (gridDim.y >> 3) + s / Gx) * 256;   // token
  const int nblock = (s % Gx) * 128;                          // n
  const int NT = K >> 5;               // K-tiles of 32

  f32x4 acc[4][4];
  const f32x4 zero = {0.f, 0.f, 0.f, 0.f};
#pragma unroll
  for (int a = 0; a < 4; a++)
#pragma unroll
    for (int b = 0; b < 4; b++) acc[a][b] = zero;

  // Staging: thread t -> row t>>2, 16B slot t&3 of the 64B k-row.
  // Source k-slot inverse-swizzled: sl = (t&3) ^ ((row&6)>>1).
  const int rw = tid >> 2;                       // 0..127
  const int sl = (tid & 3) ^ ((tid >> 3) & 3);
  const int wrow = nblock + rw;
  const int cwr  = wrow < NW ? wrow : NW - 1;    // clamp (exact fit at all
                                                 // current call sites)
  const unsigned short* sW  = W   + (size_t)cwr * K + sl * 8;
  const unsigned short* sB0 = Act + (size_t)(mblock + rw)       * K + sl * 8;
  const unsigned short* sB1 = Act + (size_t)(mblock + 128 + rw) * K + sl * 8;

  // Read-side swizzle: rows are X*16+l15 -> row&6 == l15&6, constant per lane
  const int swz = (quad * 8) ^ ((l15 & 6) << 2);   // halfword offset XOR

  // prologue: stage tiles 0,1 into bufs 0,1 (3 glds each)
#pragma unroll
  for (int t = 0; t < 2; ++t) {
    unsigned short* d = S + t * 12288 + tid * 8;
    GL2LDS16(sW  + t * 32, d);
    GL2LDS16(sB0 + t * 32, d + 4096);
    GL2LDS16(sB1 + t * 32, d + 8192);
  }
  asm volatile("s_waitcnt vmcnt(3)" ::: "memory");   // tile 0 landed
  __builtin_amdgcn_s_barrier();
  __builtin_amdgcn_sched_barrier(0);

  int bC = 0;   // buffer holding tile kt
  int bS = 2;   // buffer receiving tile kt+2
  for (int kt = 0; kt < NT; ++kt) {
    const unsigned short* SA = S + bC * 12288;
    const unsigned short* SB = SA + 4096;

    f16x8 af[4], bf[4];
#pragma unroll
    for (int t4 = 0; t4 < 4; t4++)
      af[t4] = *(const f16x8*)(SA + (wr * 64 + t4 * 16 + l15) * 32 + swz);
#pragma unroll
    for (int t4 = 0; t4 < 4; t4++)
      bf[t4] = *(const f16x8*)(SB + (wc * 64 + t4 * 16 + l15) * 32 + swz);

    // stage tile kt+2 into buf bS (read last at tile kt-1; reads drained
    // before the previous boundary barrier)
    if (kt + 2 < NT) {
      const int kb = (kt + 2) * 32;
      unsigned short* d = S + bS * 12288 + tid * 8;
      GL2LDS16(sW  + kb, d);
      GL2LDS16(sB0 + kb, d + 4096);
      GL2LDS16(sB1 + kb, d + 8192);
    }

    __builtin_amdgcn_s_barrier();
    asm volatile("s_waitcnt lgkmcnt(0)" ::: "memory");
    __builtin_amdgcn_sched_barrier(0);
    __builtin_amdgcn_s_setprio(1);
#pragma unroll
    for (int tn = 0; tn < 4; tn++)
#pragma unroll
      for (int tm = 0; tm < 4; tm++)
        acc[tn][tm] = __builtin_amdgcn_mfma_f32_16x16x32_f16(
            af[tn], bf[tm], acc[tn][tm], 0, 0, 0);
    __builtin_amdgcn_s_setprio(0);

    // boundary: tile kt+1 must have landed; keep kt+2 in flight (counted)
    if (kt < NT - 1) {
      if (kt + 2 < NT) asm volatile("s_waitcnt vmcnt(3)" ::: "memory");
      else             asm volatile("s_waitcnt vmcnt(0)" ::: "memory");
      __builtin_amdgcn_s_barrier();
      __builtin_amdgcn_sched_barrier(0);
    }
    bC = bC == 2 ? 0 : bC + 1;
    bS = bS == 2 ? 0 : bS + 1;
  }

  {
    float loss = 0.f;
#pragma unroll
    for (int tn = 0; tn < 4; tn++) {
      const int n = nblock + wr * 64 + tn * 16 + quad * 4;
#pragma unroll
      for (int tm = 0; tm < 4; tm++) {
        const int token = mblock + wc * 64 + tm * 16 + l15;
        const f32x4 v = acc[tn][tm];
        const float nrm =
            sqrtf(v[0] * v[0] + v[1] * v[1] + v[2] * v[2] + v[3] * v[3]);
        const float inv = 1.f / (nrm + 1e-8f);
        ushort4 u;
        u.x = f2h(v[0] * inv); u.y = f2h(v[1] * inv);
        u.z = f2h(v[2] * inv); u.w = f2h(v[3] * inv);
        *(ushort4*)&OutB[(size_t)token * 1024 + n] = u;
        if constexpr (EPI == 2) loss += fabsf(v[0] * inv);
      }
    }
    if constexpr (EPI == 2) {
#pragma unroll
      for (int off = 32; off > 0; off >>= 1) loss += __shfl_down(loss, off);
      if (lane == 0) lsum[wave] = loss;
      __syncthreads();
      if (tid == 0) {
        float t = 0.f;
#pragma unroll
        for (int w8 = 0; w8 < 8; w8++) t += lsum[w8];
        atomicAdd(OutF, t * (1.f / 8388608.f));
      }
    }
  }
}

// ---------------------------------------------------------------------------
// 8-phase 256x256 GEMM (E6/E7 expansion + head). BK=64, dbuf-2 slots
// (128 KB LDS, 8 waves 2x4, per-wave C 128x64). 8 phases/iter; B-frags held
// in regs across 4 quadrant phases; one half-tile glds stage per phase;
// vmcnt(4) gates at phase 3/7 only. Swizzle: read 16B-slot
// (ksub*4+quad)^(row&7); inverse on glds source slot.
// Pressure fix: staging addresses = 2 per-lane bases (pWb/pBb) + uniform
// group stride oG (8 per-lane pointers + clamp caused a spill at the
// 256-reg edge under co-compilation perturbation, R14).
// W must have >= nblock+256 rows at every call site (WH padded to 512).
// EPI: 0 = expansion step; 3 = head (fp32, n<257 masked).
// Requires K multiple of 128 (call sites 256/512/1024).
// ---------------------------------------------------------------------------
template <int EPI>
__global__ __launch_bounds__(512, 2) void gemm_8ph(
    const unsigned short* __restrict__ W,
    const unsigned short* __restrict__ Act,
    unsigned short* __restrict__ OutB, float* __restrict__ OutF,
    int K, int NW, int ldout) {
  __shared__ unsigned short S[65536];   // 2 slots x (A 16384 | B 16384) hw

  const int tid  = threadIdx.x;
  const int wave = tid >> 6;
  const int lane = tid & 63;
  const int l15  = lane & 15;
  const int quad = lane >> 4;
  const int wr   = wave >> 2;          // 0..1  n half (128 rows)
  const int wc   = wave & 3;           // 0..3  token quarter (64 cols)

  const int Gx = gridDim.x;
  const int L  = blockIdx.y * Gx + blockIdx.x;
  const int j  = L & 7;
  const int s  = L >> 3;
  const int mblock = (j * (gridDim.y >> 3) + s / Gx) * 256;   // token
  const int nblock = (s % Gx) * 256;                          // n
  const int NI = K >> 7;               // iters of 128 k (2 K-steps of 64)

  f32x4 acc[8][4];
  const f32x4 zero = {0.f, 0.f, 0.f, 0.f};
#pragma unroll
  for (int a = 0; a < 8; a++)
#pragma unroll
    for (int b = 0; b < 4; b++) acc[a][b] = zero;

  // Staging: thread covers row r8 = tid>>3 of each 64-row group; source
  // 16B-slot inverse-swizzled s8 = (tid&7)^(r8&7). Group g (0..3) of W/B
  // starts at uniform offset g*oG from the per-lane base.
  const int r8 = tid >> 3;
  const int s8 = (tid & 7) ^ (r8 & 7);
  const size_t oG = (size_t)64 * K;    // 64-row group stride (elements)
  const unsigned short* pWb = W   + (size_t)nblock * K + r8 * K + s8 * 8;
  const unsigned short* pBb = Act + (size_t)mblock * K + r8 * K + s8 * 8;

  const int lrow = l15 * 64;                          // hw
  const int ksw0 = ((quad)     ^ (l15 & 7)) * 8;      // ksub 0 16B-slot
  const int ksw1 = ((4 + quad) ^ (l15 & 7)) * 8;      // ksub 1

  // prologue: A(0), B(0) -> slot0; B(1) -> slot1
  STG(0, 0, 0, pWb, 0);  STG(0, 0, 1, pWb, 0);
  STG(0, 1, 0, pBb, 0);  STG(0, 1, 1, pBb, 0);
  STG(1, 1, 0, pBb, 64); STG(1, 1, 1, pBb, 64);
  asm volatile("s_waitcnt vmcnt(4)" ::: "memory");
  __builtin_amdgcn_s_barrier();
  __builtin_amdgcn_sched_barrier(0);

  f16x8 bfr[4][2];
  for (int i = 0; i < NI; ++i) {
    const bool nl = (i < NI - 1);
    const int kA1 = (2 * i + 1) * 64;      // A(2i+1) -> slot1
    const int k2  = (2 * i + 2) * 64;      // -> slot0
    const int k3  = (2 * i + 3) * 64;      // -> slot1
#pragma unroll
    for (int p = 0; p < 8; ++p) {
      const int q  = p & 3;
      const int sb = (p >> 2) * 32768;
      if (q == 0) {
#pragma unroll
        for (int c = 0; c < 4; ++c) {
          const unsigned short* bp = S + sb + 16384 + (wc * 64 + c * 16) * 64
                                       + lrow;
          bfr[c][0] = *(const f16x8*)(bp + ksw0);
          bfr[c][1] = *(const f16x8*)(bp + ksw1);
        }
      }
      f16x8 af[2][2];
#pragma unroll
      for (int f = 0; f < 2; ++f) {
        const unsigned short* ap = S + sb + (wr * 128 + q * 32 + f * 16) * 64
                                     + lrow;
        af[f][0] = *(const f16x8*)(ap + ksw0);
        af[f][1] = *(const f16x8*)(ap + ksw1);
      }
      if      (p == 0) { STG(1, 0, 0, pWb, kA1); }
      else if (p == 1) { STG(1, 0, 1, pWb, kA1); }
      else if (p == 2) { if (nl) STG(0, 1, 0, pBb, k2); }
      else if (p == 3) { if (nl) STG(0, 1, 1, pBb, k2); }
      else if (p == 4) { if (nl) STG(0, 0, 0, pWb, k2); }
      else if (p == 5) { if (nl) STG(0, 0, 1, pWb, k2); }
      else if (p == 6) { if (nl) STG(1, 1, 0, pBb, k3); }
      else             { if (nl) STG(1, 1, 1, pBb, k3); }

      __builtin_amdgcn_s_barrier();
      asm volatile("s_waitcnt lgkmcnt(0)" ::: "memory");
      __builtin_amdgcn_sched_barrier(0);
      __builtin_amdgcn_s_setprio(1);
#pragma unroll
      for (int f = 0; f < 2; ++f)
#pragma unroll
        for (int c = 0; c < 4; ++c) {
          acc[q * 2 + f][c] = __builtin_amdgcn_mfma_f32_16x16x32_f16(
              af[f][0], bfr[c][0], acc[q * 2 + f][c], 0, 0, 0);
          acc[q * 2 + f][c] = __builtin_amdgcn_mfma_f32_16x16x32_f16(
              af[f][1], bfr[c][1], acc[q * 2 + f][c], 0, 0, 0);
        }
      __builtin_amdgcn_s_setprio(0);

      if (p == 3) {
        if (nl) asm volatile("s_waitcnt vmcnt(4)" ::: "memory");
        else    asm volatile("s_waitcnt vmcnt(0)" ::: "memory");
        __builtin_amdgcn_s_barrier();
        __builtin_amdgcn_sched_barrier(0);
      } else if (p == 7) {
        if (nl) {
          asm volatile("s_waitcnt vmcnt(4)" ::: "memory");
          __builtin_amdgcn_s_barrier();
          __builtin_amdgcn_sched_barrier(0);
        }
      } else {
        __builtin_amdgcn_s_barrier();
      }
    }
  }

  if constexpr (EPI == 0) {
#pragma unroll
    for (int tn = 0; tn < 8; tn++) {
      const int n = nblock + wr * 128 + tn * 16 + quad * 4;
#pragma unroll
      for (int tm = 0; tm < 4; tm++) {
        const int token = mblock + wc * 64 + tm * 16 + l15;
        const f32x4 v = acc[tn][tm];
        const unsigned short* ip = Act + (size_t)token * K + n;
        const float i0 = h2f(ip[0]), i1 = h2f(ip[1]);
        const float i2 = h2f(ip[2]), i3 = h2f(ip[3]);
        const float d0 = tanhf(v[0]), d1 = tanhf(v[1]);
        const float d2 = tanhf(v[2]), d3 = tanhf(v[3]);
        ushort4 up, um;
        up.x = f2h(i0 + d0); up.y = f2h(i1 + d1);
        up.z = f2h(i2 + d2); up.w = f2h(i3 + d3);
        um.x = f2h(i0 - d0); um.y = f2h(i1 - d1);
        um.z = f2h(i2 - d2); um.w = f2h(i3 - d3);
        *(ushort4*)&OutB[(size_t)token * ldout + n] = up;
        *(ushort4*)&OutB[(size_t)token * ldout + NW + n] = um;
      }
    }
  } else {  // EPI == 3 : head
#pragma unroll
    for (int tn = 0; tn < 8; tn++) {
      const int n = nblock + wr * 128 + tn * 16 + quad * 4;
      if (n < 257) {
#pragma unroll
        for (int tm = 0; tm < 4; tm++) {
          const int token = mblock + wc * 64 + tm * 16 + l15;
          const f32x4 v = acc[tn][tm];
#pragma unroll
          for (int r = 0; r < 4; r++)
            if (n + r < 257) OutF[(size_t)token * 257 + n + r] = v[r];
        }
      }
    }
  }
}

// ---------------------------------------------------------------------------
extern "C" void kernel_launch(void* const* d_in, const int* in_sizes, int n_in,
                              void* d_out, int out_size, void* d_ws,
                              size_t ws_size, hipStream_t stream) {
  const int*   x    = (const int*)d_in[0];
  const float* emb  = (const float*)d_in[1];
  const float* we0  = (const float*)d_in[2];
  const float* we1  = (const float*)d_in[3];
  const float* we2  = (const float*)d_in[4];
  const float* we3  = (const float*)d_in[5];
  const float* we4  = (const float*)d_in[6];
  const float* we5  = (const float*)d_in[7];
  const float* we6  = (const float*)d_in[8];
  const float* we7  = (const float*)d_in[9];
  const float* wlay = (const float*)d_in[10];
  const float* wh   = (const float*)d_in[11];
  float* out = (float*)d_out;

  // workspace layout (~142 MiB)
  char* p = (char*)d_ws;
  auto alloc = [&](size_t bytes) {
    void* r = (void*)p;
    p += (bytes + 255) & ~(size_t)255;
    return r;
  };
  unsigned short* act0 = (unsigned short*)alloc(32768ull * 1024 * 2);
  unsigned short* act1 = (unsigned short*)alloc(32768ull * 1024 * 2);
  unsigned short* E4 = (unsigned short*)alloc(128 * 64 * 2);
  unsigned short* E5 = (unsigned short*)alloc(128 * 128 * 2);
  unsigned short* E6 = (unsigned short*)alloc(256 * 256 * 2);
  unsigned short* E7 = (unsigned short*)alloc(512 * 512 * 2);
  unsigned short* EL = (unsigned short*)alloc(6ull * 1024 * 1024 * 2);
  unsigned short* WH = (unsigned short*)alloc(512 * 1024 * 2);

  // zero the stability-loss slot (d_out is poisoned before every launch)
  hipMemsetAsync(out + 8421376, 0, 4, stream);

  // weight expansion (Hamilton blocks -> real fp16 matrices)
  expand_ham<<<dim3(8192 / 256), 256, 0, stream>>>(we4, E4, 16, 6, 128 * 64);
  expand_ham<<<dim3(16384 / 256), 256, 0, stream>>>(we5, E5, 32, 7, 128 * 128);
  expand_ham<<<dim3(65536 / 256), 256, 0, stream>>>(we6, E6, 64, 8, 256 * 256);
  expand_ham<<<dim3(262144 / 256), 256, 0, stream>>>(we7, E7, 128, 9,
                                                     512 * 512);
  expand_ham6<<<dim3(6 * 1048576 / 256), 256, 0, stream>>>(wlay, EL);
  conv_head<<<dim3(512 * 1024 / 256), 256, 0, stream>>>(wh, WH);

  // embed + expansion steps 0..3 -> act0 [32768][64] fp16
  embed_expand<<<dim3(128), 256, 0, stream>>>(x, emb, we0, we1, we2, we3, act0);

  // expansion steps 4..5 (small K) on the old 128x128 kernel
  gemm_epi0<<<dim3(1, 256), 256, 0, stream>>>(E4, act0, act1, 64, 64, 128);
  gemm_epi0<<<dim3(1, 256), 256, 0, stream>>>(E5, act1, act0, 128, 128, 256);
  // expansion steps 6..7 on the 8-phase kernel (EPI 0)
  gemm_8ph<0><<<dim3(1, 128), 512, 0, stream>>>(E6, act0, act1, nullptr, 256,
                                                256, 512);
  gemm_8ph<0><<<dim3(2, 128), 512, 0, stream>>>(E7, act1, act0, nullptr, 512,
                                                512, 1024);

  // 6 quaternion-linear + normalize layers on the R8 kernel
  unsigned short* a = act0;
  unsigned short* b = act1;
  for (int d = 0; d < 5; d++) {
    gemm8p<1><<<dim3(8, 128), 512, 0, stream>>>(EL + (size_t)d * 1048576, a, b,
                                                nullptr, 1024, 1024, 1024);
    unsigned short* t = a; a = b; b = t;
  }
  gemm8p<2><<<dim3(8, 128), 512, 0, stream>>>(EL + 5ull * 1048576, a, b,
                                              out + 8421376, 1024, 1024, 1024);
  { unsigned short* t = a; a = b; b = t; }

  // head: logits = h @ w_head^T  (WH zero-padded to 512 rows -> 2 exact
  // 256-row n-tiles; masked stores n<257)
  gemm_8ph<3><<<dim3(2, 128), 512, 0, stream>>>(WH, a, nullptr, out, 1024, 0,
                                                0);
}